// Round 11
// baseline (1036.474 us; speedup 1.0000x reference)
//
#include <hip/hip_runtime.h>
#include <hip/hip_bf16.h>

#define DD 512
#define BM 64
#define THREADS 1024

typedef __attribute__((ext_vector_type(8))) short short8;   // 8 bf16 = 4 VGPRs (MFMA A/B frag)
typedef __attribute__((ext_vector_type(4))) float f32x4;    // MFMA C/D frag

__device__ __forceinline__ unsigned short f2bf(float f) {
  union { float f; unsigned u; } v; v.f = f;
  unsigned r = v.u + 0x7FFFu + ((v.u >> 16) & 1u);  // RNE
  return (unsigned short)(r >> 16);
}

// Pack kernel (K x N fp32, row-major) into MFMA-fragment-major bf16:
//   Bpack[((nb*16 + kt)*64 + lane)*8 + j]  holds  B[k][n]
//   with n = nb*16 + (lane&15), k = kt*32 + (lane>>4)*8 + j.
__global__ void prep_bpack(const float* __restrict__ W, unsigned short* __restrict__ Bpack) {
  const int tid = blockIdx.x * blockDim.x + threadIdx.x;   // 262144 threads
  const int n = tid & 511, k = tid >> 9;
  const float w = W[(size_t)k * DD + n];                   // coalesced read
  const int nb = n >> 4, lo = n & 15;
  const int kt = k >> 5, hi = (k >> 3) & 3, j = k & 7;
  const int lane = hi * 16 + lo;
  Bpack[(((size_t)(nb * 16 + kt)) * 64 + lane) * 8 + j] = f2bf(w);
}

// Fused: LN -> relu -> bf16 -> GEMM(Bpack) -> +x +bias.
// Block = 64 rows x 512 cols, 1024 threads = 16 waves; wave w owns a 64x32
// strip (each B column-strip read by exactly ONE wave -> 2 GB total B L2).
// Residual folded into accumulator init (acc = x + bias, C/D layout, L2-hot)
// -> no Xlds -> LDS 64 KB -> 2 blocks/CU -> cross-block phase overlap.
__global__ __launch_bounds__(THREADS, 8)   // 8 waves/EU = 2 blocks/CU, VGPR cap 64
void fused_ln_gemm(const float* __restrict__ x, const float* __restrict__ lns,
                   const float* __restrict__ lnb, const unsigned short* __restrict__ Bpack,
                   const float* __restrict__ bias, float* __restrict__ out) {
  __shared__ unsigned short Alds[BM * 512];   // 64 KB, h bf16, XOR-swizzled rows

  const int t = threadIdx.x;
  const int lane = t & 63, lo = lane & 15, hi = lane >> 4;
  const int w = t >> 6;                       // wave id 0..15 -> 32-col strip
  const long row0 = (long)blockIdx.x * BM;

  // ---------------- LN + relu phase: 16 threads per row (64 rows) -------
  {
    const int r = t >> 4, g = t & 15;
    const float* xr = x + (row0 + r) * DD + g * 4;
    float4 v[8];
    float s = 0.f, s2 = 0.f;
    #pragma unroll
    for (int i = 0; i < 8; ++i) {
      v[i] = *(const float4*)(xr + i * 64);
      s  += (v[i].x + v[i].y) + (v[i].z + v[i].w);
      s2 += v[i].x * v[i].x + v[i].y * v[i].y + v[i].z * v[i].z + v[i].w * v[i].w;
    }
    #pragma unroll
    for (int m = 1; m < 16; m <<= 1) {   // 16-lane group reduce (within wave)
      s  += __shfl_xor(s,  m, 64);
      s2 += __shfl_xor(s2, m, 64);
    }
    const float mu   = s * (1.f / 512.f);
    const float var  = fmaxf(s2 * (1.f / 512.f) - mu * mu, 0.f);
    const float rstd = rsqrtf(var + 1e-6f);
    #pragma unroll
    for (int i = 0; i < 8; ++i) {
      const int c = g * 4 + i * 64;
      const float4 sc = *(const float4*)(lns + c);
      const float4 bi = *(const float4*)(lnb + c);
      ushort4 hu;
      hu.x = f2bf(fmaxf((v[i].x - mu) * rstd * sc.x + bi.x, 0.f));
      hu.y = f2bf(fmaxf((v[i].y - mu) * rstd * sc.y + bi.y, 0.f));
      hu.z = f2bf(fmaxf((v[i].z - mu) * rstd * sc.z + bi.z, 0.f));
      hu.w = f2bf(fmaxf((v[i].w - mu) * rstd * sc.w + bi.w, 0.f));
      // byte addr (r*1024 + c*2) ^ ((r&7)<<4) — 8B-aligned stays 8B-aligned
      const unsigned a = (unsigned)(r * 1024 + g * 8 + i * 128) ^ (unsigned)((r & 7) << 4);
      *(ushort4*)((char*)Alds + a) = hu;
    }
  }

  // ------- acc = x + bias (C/D layout, L1/L2-hot), pre-barrier ----------
  const int col0 = w * 32 + lo;
  const float bv0 = bias[col0];
  const float bv1 = bias[col0 + 16];

  f32x4 acc[4][2];
  {
    const float* xc = x + (row0 + hi * 4) * DD + col0;
    #pragma unroll
    for (int m = 0; m < 4; ++m) {
      #pragma unroll
      for (int q = 0; q < 4; ++q) {
        const float* r = xc + (m * 16 + q) * DD;
        acc[m][0][q] = r[0]  + bv0;
        acc[m][1][q] = r[16] + bv1;
      }
    }
  }
  __syncthreads();

  // ------- GEMM phase: pinned depth-3 B ring, no barriers in K-loop -----
  unsigned abase[4];
  #pragma unroll
  for (int m = 0; m < 4; ++m)
    abase[m] = (unsigned)((m * 16 + lo) * 1024 + hi * 16);
  const unsigned asw = (unsigned)((lo & 7) << 4);   // (m*16+lo)&7 == lo&7

  // B frag (nb = w*2 + nt, kt): Bpack8 + ((w*2+nt)*16 + kt)*64 + lane
  const short8* bbase = (const short8*)Bpack + (size_t)(w * 2) * 1024 + lane;

  short8 rb[3][2];   // depth-3 prefetch ring; indices static after unroll
#define LOADB(s, kt)                                                          \
  { rb[s][0] = bbase[(0 * 16 + (kt)) * 64];                                   \
    rb[s][1] = bbase[(1 * 16 + (kt)) * 64]; }

  LOADB(0, 0);
  LOADB(1, 1);
  __builtin_amdgcn_sched_barrier(0);   // pin: 4 loads issued before any MFMA

  #pragma unroll
  for (int kt = 0; kt < 16; ++kt) {
    const int cur = kt % 3;
    if (kt + 2 < 16) {
      const int nxt = (kt + 2) % 3;
      LOADB(nxt, kt + 2);                // issue kt+2's loads FIRST
    }
    __builtin_amdgcn_sched_barrier(0);   // loads may not sink below this
    short8 a[4];
    #pragma unroll
    for (int m = 0; m < 4; ++m)
      a[m] = *(const short8*)((const char*)Alds + ((abase[m] + (unsigned)kt * 64) ^ asw));
    #pragma unroll
    for (int m = 0; m < 4; ++m) {
      acc[m][0] = __builtin_amdgcn_mfma_f32_16x16x32_bf16(a[m], rb[cur][0], acc[m][0], 0, 0, 0);
      acc[m][1] = __builtin_amdgcn_mfma_f32_16x16x32_bf16(a[m], rb[cur][1], acc[m][1], 0, 0, 0);
    }
  }
#undef LOADB

  // ---------------- epilogue: pure store ---------------------------------
  float* oc = out + (row0 + hi * 4) * DD + col0;
  #pragma unroll
  for (int m = 0; m < 4; ++m) {
    #pragma unroll
    for (int q = 0; q < 4; ++q) {
      float* o = oc + (m * 16 + q) * DD;
      o[0]  = acc[m][0][q];
      o[16] = acc[m][1][q];
    }
  }
}

extern "C" void kernel_launch(void* const* d_in, const int* in_sizes, int n_in,
                              void* d_out, int out_size, void* d_ws, size_t ws_size,
                              hipStream_t stream) {
  const float* x    = (const float*)d_in[0];
  const float* lns  = (const float*)d_in[1];
  const float* lnb  = (const float*)d_in[2];
  const float* W    = (const float*)d_in[3];
  const float* bias = (const float*)d_in[4];
  float* out = (float*)d_out;
  unsigned short* Bpack = (unsigned short*)d_ws;   // 512KB scratch

  const int nrows = in_sizes[0] / DD;

  prep_bpack<<<DD * DD / 256, 256, 0, stream>>>(W, Bpack);
  fused_ln_gemm<<<nrows / BM, THREADS, 0, stream>>>(x, lns, lnb, Bpack, bias, out);
}